// Round 8
// baseline (1177.381 us; speedup 1.0000x reference)
//
#include <hip/hip_runtime.h>
#include <hip/hip_bf16.h>

typedef __attribute__((ext_vector_type(8))) short s16x8;
typedef __attribute__((ext_vector_type(4))) float f32x4;

#define MFMA_B16(a, b, c) __builtin_amdgcn_mfma_f32_16x16x32_bf16((a), (b), (c), 0, 0, 0)

static __device__ __forceinline__ short f2bf(float f) {
    __hip_bfloat16 h = __float2bfloat16(f);
    return __builtin_bit_cast(short, h);
}
static __device__ __forceinline__ float rcp_f(float x) {
    return __builtin_amdgcn_rcpf(x);
}

// pre-pass: X fp32 -> bf16 in workspace
__global__ void xcvt_kernel(const float* __restrict__ X, short* __restrict__ Xb, int n) {
    int i = (blockIdx.x * 256 + threadIdx.x) * 4;
    if (i < n) {
        float4 v = *(const float4*)(X + i);
        short4 o;
        o.x = f2bf(v.x); o.y = f2bf(v.y); o.z = f2bf(v.z); o.w = f2bf(v.w);
        *(short4*)(Xb + i) = o;
    }
}

// Ensemble LSTM, batch-split-8: WG = (series n, batch-group of 4). 256 WGs = 256 CUs.
// R8 = R4 (best schedule; 329 us) with ONE change: the pred head is distributed
// across waves 0..3 — each computes a single k-chunk MFMA (Af[w].Bp[w]) and
// accumulates the partial via LDS atomicAdd (ds_add_f32). This removes the
// 4-chained-MFMA burst on the rotating wave that every barrier had to wait for
// (slowest-wave skew ~78 -> ~25 cyc). Pred stage re-laid out [t][b] so the
// adds spread across banks. All other scheduling identical to R4 (inline-asm
// barriers and issue-reordering measured as regressions in R5-R7).
template<bool BF16X>
__global__ __launch_bounds__(512, 2)
void clstm_kernel(const float* __restrict__ X,
                  const short* __restrict__ Xb,
                  const float* __restrict__ W_ih,
                  const float* __restrict__ W_hh,
                  const float* __restrict__ b_ih,
                  const float* __restrict__ b_hh,
                  const float* __restrict__ W_out,
                  const float* __restrict__ b_out,
                  float* __restrict__ out)
{
    constexpr int B = 32, T = 512, N = 32, H = 128, G = 512;  // G = 4H
    constexpr int HT_OFF = B * T * N;
    constexpr int CT_OFF = HT_OFF + N * B * H;
    constexpr int PRED_OFF = 8192;
    constexpr float C1 = 1.4426950408889634f;   // log2(e)

    __shared__ __align__(16) unsigned char smem[16384];

    const int tid  = threadIdx.x;
    const int w    = tid >> 6;   // wave 0..7
    const int L    = tid & 63;
    const int col  = L & 15;
    const int quad = L >> 4;
    const int n    = blockIdx.x & 31;   // series
    const int bgrp = blockIdx.x >> 5;   // batch group (4 batches)

    // ---- loop-invariant weight fragments (fp32 -> bf16, once) ----
    s16x8 Bh[4][4];  // [gate tt][kt]
    s16x8 Bx[4];     // [gate tt]  k = input p 0..31
    f32x4 biasv[4];  // persistent MFMA C operand (bias broadcast)
#pragma unroll
    for (int tt = 0; tt < 4; ++tt) {
        const int g = (w + 8 * tt) * 16 + col;
        const float* whr = W_hh + ((size_t)n * G + g) * H + quad * 8;
#pragma unroll
        for (int kt = 0; kt < 4; ++kt) {
            const float* p = whr + kt * 32;
#pragma unroll
            for (int jj = 0; jj < 8; ++jj) Bh[tt][kt][jj] = f2bf(p[jj]);
        }
        const float* wir = W_ih + ((size_t)n * G + g) * N + quad * 8;
#pragma unroll
        for (int jj = 0; jj < 8; ++jj) Bx[tt][jj] = f2bf(wir[jj]);
        const float bb = b_ih[n * G + g] + b_hh[n * G + g];
        biasv[tt] = (f32x4){bb, bb, bb, bb};
    }

    // ---- pred tile: B col 0 = W_out; wave w (w<4) uses chunk kt=w ----
    s16x8 Bp[4];
    const float bo = b_out[n];
    const f32x4 bov   = (f32x4){bo, bo, bo, bo};
    const f32x4 zerov = (f32x4){0.f, 0.f, 0.f, 0.f};
#pragma unroll
    for (int kt = 0; kt < 4; ++kt) {
        const float* wp = W_out + n * H + kt * 32 + quad * 8;
#pragma unroll
        for (int jj = 0; jj < 8; ++jj)
            Bp[kt][jj] = (col == 0) ? f2bf(wp[jj]) : (short)0;
    }

    // ---- h writer offset: cell (batch=quad -> m=4*quad, j=w*16+col) ----
    int wboff;
    {
        const int j = w * 16 + col;
        wboff = (j >> 5) * 1024 + (((((j >> 3) & 3) << 4) | (quad << 2)) * 16) + (j & 7) * 2;
    }

    // ---- x loader: lanes with col%4==0 carry batch b=col>>2 at row m=col ----
    const bool xactive = (col & 3) == 0;
    const int  xb      = bgrp * 4 + (col >> 2);
    const float* xp  = X + ((size_t)xb * T) * N + quad * 8;
    const short* xbp = BF16X ? (Xb + ((size_t)xb * T) * N + quad * 8) : nullptr;

    auto loadx = [&](int t) -> s16x8 {
        s16x8 r = (s16x8)(short)0;
        if (xactive) {
            if constexpr (BF16X) {
                r = *(const s16x8*)(xbp + (size_t)t * N);
            } else {
                float4 lo = *(const float4*)(xp + (size_t)t * N);
                float4 hi = *(const float4*)(xp + (size_t)t * N + 4);
                r[0] = f2bf(lo.x); r[1] = f2bf(lo.y); r[2] = f2bf(lo.z); r[3] = f2bf(lo.w);
                r[4] = f2bf(hi.x); r[5] = f2bf(hi.y); r[6] = f2bf(hi.z); r[7] = f2bf(hi.w);
            }
        }
        return r;
    };

    // zero frag buffers (pad rows must stay 0) + pred stage (accumulated into)
    *(float4*)(smem + tid * 16)        = make_float4(0.f, 0.f, 0.f, 0.f);
    *(float4*)(smem + 8192 + tid * 16) = make_float4(0.f, 0.f, 0.f, 0.f);

    float cst = 0.f, hlast = 0.f;

    // prologue: accN = partial gates for t=0; prefetch x_1, x_2
    f32x4 accN[4];
    {
        s16x8 x0 = loadx(0);
#pragma unroll
        for (int tt = 0; tt < 4; ++tt)
            accN[tt] = MFMA_B16(x0, Bx[tt], biasv[tt]);
    }
    s16x8 xA = loadx(1);
    s16x8 xB = loadx(2);

    __syncthreads();

#define STEP(P, TCUR)                                                               \
    {                                                                               \
        const unsigned char* rb = smem + (P) * 4096;                                \
        s16x8 Af[4];                                                                \
        _Pragma("unroll")                                                           \
        for (int kt = 0; kt < 4; ++kt)                                              \
            Af[kt] = *(const s16x8*)(rb + kt * 1024 + L * 16);                      \
        /* Wh GEMM, C = accN (bias + x_t.Wx, ready since last step) */              \
        f32x4 acc[4];                                                               \
        _Pragma("unroll")                                                           \
        for (int tt = 0; tt < 4; ++tt)                                              \
            acc[tt] = MFMA_B16(Af[0], Bh[tt][0], accN[tt]);                         \
        _Pragma("unroll")                                                           \
        for (int kt = 1; kt < 4; ++kt) {                                            \
            _Pragma("unroll")                                                       \
            for (int tt = 0; tt < 4; ++tt)                                          \
                acc[tt] = MFMA_B16(Af[kt], Bh[tt][kt], acc[tt]);                    \
        }                                                                           \
        /* distributed pred: wave w<4 contributes chunk kt=w of h_{TCUR-1}.Wout */  \
        if (w < 4) {                                                                \
            f32x4 pacc = MFMA_B16(Af[w], Bp[w], (w == 0) ? bov : zerov);            \
            if ((TCUR) > 0 && col == 0)                                             \
                atomicAdd((float*)(smem + PRED_OFF + ((((TCUR) - 1) << 2) + quad) * 4), \
                          pacc[0]);                                                 \
        }                                                                           \
        /* next-step partial gates (h-independent) */                               \
        _Pragma("unroll")                                                           \
        for (int tt = 0; tt < 4; ++tt)                                              \
            accN[tt] = MFMA_B16(xA, Bx[tt], biasv[tt]);                             \
        xA = xB;                                                                    \
        xB = loadx(((TCUR) + 3 < T) ? (TCUR) + 3 : T - 1);                          \
        /* epilogue: fused-rcp activations (1 cell/lane) */                         \
        {                                                                           \
            const float iv = acc[0][0], fv = acc[1][0];                             \
            const float gv = acc[2][0], ov = acc[3][0];                             \
            const float ei = exp2f(-C1 * iv);                                       \
            const float ef = exp2f(-C1 * fv);                                       \
            const float eg = exp2f(-2.0f * C1 * gv);                                \
            const float eo = exp2f(-C1 * ov);                                       \
            const float sf = rcp_f(1.0f + ef);                                      \
            const float itg = (1.0f - eg) * rcp_f((1.0f + ei) * (1.0f + eg));       \
            const float cc = __builtin_fmaf(sf, cst, itg);                          \
            cst = cc;                                                               \
            const float ec = exp2f(-2.0f * C1 * cc);                                \
            const float hv = (1.0f - ec) * rcp_f((1.0f + eo) * (1.0f + ec));        \
            hlast = hv;                                                             \
            *(short*)(smem + ((P) ^ 1) * 4096 + wboff) = f2bf(hv);                  \
        }                                                                           \
        __syncthreads();                                                            \
    }

#pragma unroll 1
    for (int t2 = 0; t2 < T; t2 += 2) {
        STEP(0, t2)
        STEP(1, t2 + 1)
    }
#undef STEP

    // ---- tail pred: t = T-1 uses h_{T-1}, sitting in buffer 0 (direct store) ----
    if (w == 0) {
        f32x4 pacc = bov;
#pragma unroll
        for (int kt = 0; kt < 4; ++kt) {
            s16x8 Af = *(const s16x8*)(smem + kt * 1024 + L * 16);
            pacc = MFMA_B16(Af, Bp[kt], pacc);
        }
        if (col == 0)
            *(float*)(smem + PRED_OFF + (((T - 1) << 2) + quad) * 4) = pacc[0];
    }
    __syncthreads();

    // ---- flush pred stage [t][b] -> global ----
#pragma unroll
    for (int e = tid; e < 4 * T; e += 512) {
        const int t = e >> 2, b = e & 3;
        out[((size_t)(bgrp * 4 + b) * T + t) * N + n] =
            *(const float*)(smem + PRED_OFF + e * 4);
    }

    // ---- final hT, cT ----
    {
        const int bglob = bgrp * 4 + quad;
        const int j = w * 16 + col;
        out[HT_OFF + ((size_t)n * B + bglob) * H + j] = hlast;
        out[CT_OFF + ((size_t)n * B + bglob) * H + j] = cst;
    }
}

extern "C" void kernel_launch(void* const* d_in, const int* in_sizes, int n_in,
                              void* d_out, int out_size, void* d_ws, size_t ws_size,
                              hipStream_t stream) {
    const float* X     = (const float*)d_in[0];
    const float* W_ih  = (const float*)d_in[1];
    const float* W_hh  = (const float*)d_in[2];
    const float* b_ih  = (const float*)d_in[3];
    const float* b_hh  = (const float*)d_in[4];
    const float* W_out = (const float*)d_in[5];
    const float* b_out = (const float*)d_in[6];
    float* out = (float*)d_out;

    const int xelems = 32 * 512 * 32;  // B*T*N
    const bool usebf = ws_size >= (size_t)xelems * sizeof(short);

    if (usebf) {
        short* Xb = (short*)d_ws;
        xcvt_kernel<<<dim3(xelems / 1024), dim3(256), 0, stream>>>(X, Xb, xelems);
        clstm_kernel<true><<<dim3(256), dim3(512), 0, stream>>>(
            X, Xb, W_ih, W_hh, b_ih, b_hh, W_out, b_out, out);
    } else {
        clstm_kernel<false><<<dim3(256), dim3(512), 0, stream>>>(
            X, nullptr, W_ih, W_hh, b_ih, b_hh, W_out, b_out, out);
    }
}

// Round 9
// 365.060 us; speedup vs baseline: 3.2252x; 3.2252x over previous
//
#include <hip/hip_runtime.h>
#include <hip/hip_bf16.h>

typedef __attribute__((ext_vector_type(8))) short s16x8;
typedef __attribute__((ext_vector_type(4))) float f32x4;

#define MFMA_B16(a, b, c) __builtin_amdgcn_mfma_f32_16x16x32_bf16((a), (b), (c), 0, 0, 0)

static __device__ __forceinline__ short f2bf(float f) {
    __hip_bfloat16 h = __float2bfloat16(f);
    return __builtin_bit_cast(short, h);
}
static __device__ __forceinline__ float rcp_f(float x) {
    return __builtin_amdgcn_rcpf(x);
}

// pre-pass: X fp32 -> bf16 in workspace
__global__ void xcvt_kernel(const float* __restrict__ X, short* __restrict__ Xb, int n) {
    int i = (blockIdx.x * 256 + threadIdx.x) * 4;
    if (i < n) {
        float4 v = *(const float4*)(X + i);
        short4 o;
        o.x = f2bf(v.x); o.y = f2bf(v.y); o.z = f2bf(v.z); o.w = f2bf(v.w);
        *(short4*)(Xb + i) = o;
    }
}

// Ensemble LSTM, batch-split-8: WG = (series n, batch-group of 4). 256 WGs = 256 CUs.
// R9 = byte-exact revert to R4 (best: 329 us rocprof). Journal of failed deltas:
//   R5/R6 x-pair packing     -> +15 us (lengthened C-operand serial chain)
//   R7 lgkm-only asm barrier -> +21 us (defeated compiler scheduling)
//   R8 LDS atomicAdd pred    -> +834 us (shared-mem fp32 atomic is not ds_add fire-and-forget)
// R4 structure: 1 cell/lane epilogue (batch b -> MFMA row 4b), weights in VGPRs,
// double-buffered frag-linear h in LDS, pred folded into a rotating-wave MFMA
// tile staged in LDS, x.W_ih partial gates computed a step ahead.
template<bool BF16X>
__global__ __launch_bounds__(512, 2)
void clstm_kernel(const float* __restrict__ X,
                  const short* __restrict__ Xb,
                  const float* __restrict__ W_ih,
                  const float* __restrict__ W_hh,
                  const float* __restrict__ b_ih,
                  const float* __restrict__ b_hh,
                  const float* __restrict__ W_out,
                  const float* __restrict__ b_out,
                  float* __restrict__ out)
{
    constexpr int B = 32, T = 512, N = 32, H = 128, G = 512;  // G = 4H
    constexpr int HT_OFF = B * T * N;
    constexpr int CT_OFF = HT_OFF + N * B * H;
    constexpr int PRED_OFF = 8192;
    constexpr float C1 = 1.4426950408889634f;   // log2(e)

    __shared__ __align__(16) unsigned char smem[16384];

    const int tid  = threadIdx.x;
    const int w    = tid >> 6;   // wave 0..7
    const int L    = tid & 63;
    const int col  = L & 15;
    const int quad = L >> 4;
    const int n    = blockIdx.x & 31;   // series
    const int bgrp = blockIdx.x >> 5;   // batch group (4 batches)

    // ---- loop-invariant weight fragments (fp32 -> bf16, once) ----
    s16x8 Bh[4][4];  // [gate tt][kt]
    s16x8 Bx[4];     // [gate tt]  k = input p 0..31
    f32x4 biasv[4];  // persistent MFMA C operand (bias broadcast)
#pragma unroll
    for (int tt = 0; tt < 4; ++tt) {
        const int g = (w + 8 * tt) * 16 + col;
        const float* whr = W_hh + ((size_t)n * G + g) * H + quad * 8;
#pragma unroll
        for (int kt = 0; kt < 4; ++kt) {
            const float* p = whr + kt * 32;
#pragma unroll
            for (int jj = 0; jj < 8; ++jj) Bh[tt][kt][jj] = f2bf(p[jj]);
        }
        const float* wir = W_ih + ((size_t)n * G + g) * N + quad * 8;
#pragma unroll
        for (int jj = 0; jj < 8; ++jj) Bx[tt][jj] = f2bf(wir[jj]);
        const float bb = b_ih[n * G + g] + b_hh[n * G + g];
        biasv[tt] = (f32x4){bb, bb, bb, bb};
    }

    // ---- pred tile: B col 0 = W_out, rotated across waves ----
    s16x8 Bp[4];
    const float bo = b_out[n];
    const f32x4 bov = (f32x4){bo, bo, bo, bo};
#pragma unroll
    for (int kt = 0; kt < 4; ++kt) {
        const float* wp = W_out + n * H + kt * 32 + quad * 8;
#pragma unroll
        for (int jj = 0; jj < 8; ++jj)
            Bp[kt][jj] = (col == 0) ? f2bf(wp[jj]) : (short)0;
    }

    // ---- h writer offset: cell (batch=quad -> m=4*quad, j=w*16+col) ----
    int wboff;
    {
        const int j = w * 16 + col;
        wboff = (j >> 5) * 1024 + (((((j >> 3) & 3) << 4) | (quad << 2)) * 16) + (j & 7) * 2;
    }

    // ---- x loader: lanes with col%4==0 carry batch b=col>>2 at row m=col ----
    const bool xactive = (col & 3) == 0;
    const int  xb      = bgrp * 4 + (col >> 2);
    const float* xp  = X + ((size_t)xb * T) * N + quad * 8;
    const short* xbp = BF16X ? (Xb + ((size_t)xb * T) * N + quad * 8) : nullptr;

    auto loadx = [&](int t) -> s16x8 {
        s16x8 r = (s16x8)(short)0;
        if (xactive) {
            if constexpr (BF16X) {
                r = *(const s16x8*)(xbp + (size_t)t * N);
            } else {
                float4 lo = *(const float4*)(xp + (size_t)t * N);
                float4 hi = *(const float4*)(xp + (size_t)t * N + 4);
                r[0] = f2bf(lo.x); r[1] = f2bf(lo.y); r[2] = f2bf(lo.z); r[3] = f2bf(lo.w);
                r[4] = f2bf(hi.x); r[5] = f2bf(hi.y); r[6] = f2bf(hi.z); r[7] = f2bf(hi.w);
            }
        }
        return r;
    };

    // zero frag buffers (pad rows must stay 0) + pred stage
    *(float4*)(smem + tid * 16)        = make_float4(0.f, 0.f, 0.f, 0.f);
    *(float4*)(smem + 8192 + tid * 16) = make_float4(0.f, 0.f, 0.f, 0.f);

    float cst = 0.f, hlast = 0.f;

    // prologue: accN = partial gates for t=0; prefetch x_1, x_2
    f32x4 accN[4];
    {
        s16x8 x0 = loadx(0);
#pragma unroll
        for (int tt = 0; tt < 4; ++tt)
            accN[tt] = MFMA_B16(x0, Bx[tt], biasv[tt]);
    }
    s16x8 xA = loadx(1);
    s16x8 xB = loadx(2);

    __syncthreads();

#define STEP(P, TCUR)                                                               \
    {                                                                               \
        const unsigned char* rb = smem + (P) * 4096;                                \
        s16x8 Af[4];                                                                \
        _Pragma("unroll")                                                           \
        for (int kt = 0; kt < 4; ++kt)                                              \
            Af[kt] = *(const s16x8*)(rb + kt * 1024 + L * 16);                      \
        f32x4 acc[4];                                                               \
        _Pragma("unroll")                                                           \
        for (int tt = 0; tt < 4; ++tt) acc[tt] = accN[tt];                          \
        _Pragma("unroll")                                                           \
        for (int kt = 0; kt < 4; ++kt) {                                            \
            _Pragma("unroll")                                                       \
            for (int tt = 0; tt < 4; ++tt)                                          \
                acc[tt] = MFMA_B16(Af[kt], Bh[tt][kt], acc[tt]);                    \
        }                                                                           \
        if (w == ((TCUR) & 7)) {                                                    \
            f32x4 pacc = bov;                                                       \
            _Pragma("unroll")                                                       \
            for (int kt = 0; kt < 4; ++kt)                                          \
                pacc = MFMA_B16(Af[kt], Bp[kt], pacc);                              \
            if ((TCUR) > 0 && col == 0)                                             \
                *(float*)(smem + PRED_OFF + ((quad << 9) + (TCUR) - 1) * 4) =       \
                    pacc[0];                                                        \
        }                                                                           \
        /* overlap window: h_t-independent partial gates for t+1 */                 \
        _Pragma("unroll")                                                           \
        for (int tt = 0; tt < 4; ++tt)                                              \
            accN[tt] = MFMA_B16(xA, Bx[tt], biasv[tt]);                             \
        xA = xB;                                                                    \
        xB = loadx(((TCUR) + 3 < T) ? (TCUR) + 3 : T - 1);                          \
        /* epilogue: fused-rcp activations (8 trans) */                             \
        {                                                                           \
            const float iv = acc[0][0], fv = acc[1][0];                             \
            const float gv = acc[2][0], ov = acc[3][0];                             \
            const float ei = exp2f(-C1 * iv);                                       \
            const float ef = exp2f(-C1 * fv);                                       \
            const float eg = exp2f(-2.0f * C1 * gv);                                \
            const float eo = exp2f(-C1 * ov);                                       \
            const float sf = rcp_f(1.0f + ef);                                      \
            const float itg = (1.0f - eg) * rcp_f((1.0f + ei) * (1.0f + eg));       \
            const float cc = __builtin_fmaf(sf, cst, itg);                          \
            cst = cc;                                                               \
            const float ec = exp2f(-2.0f * C1 * cc);                                \
            const float hv = (1.0f - ec) * rcp_f((1.0f + eo) * (1.0f + ec));        \
            hlast = hv;                                                             \
            *(short*)(smem + ((P) ^ 1) * 4096 + wboff) = f2bf(hv);                  \
        }                                                                           \
        __syncthreads();                                                            \
    }

#pragma unroll 1
    for (int t2 = 0; t2 < T; t2 += 2) {
        STEP(0, t2)
        STEP(1, t2 + 1)
    }
#undef STEP

    // ---- tail pred: t = T-1 uses h_{T-1}, sitting in buffer 0 ----
    if (w == 0) {
        f32x4 pacc = bov;
#pragma unroll
        for (int kt = 0; kt < 4; ++kt) {
            s16x8 Af = *(const s16x8*)(smem + kt * 1024 + L * 16);
            pacc = MFMA_B16(Af, Bp[kt], pacc);
        }
        if (col == 0)
            *(float*)(smem + PRED_OFF + ((quad << 9) + (T - 1)) * 4) = pacc[0];
    }
    __syncthreads();

    // ---- flush pred stage -> global ----
#pragma unroll
    for (int e = tid; e < 4 * T; e += 512) {
        const int b = e >> 9, t = e & (T - 1);
        out[((size_t)(bgrp * 4 + b) * T + t) * N + n] =
            *(const float*)(smem + PRED_OFF + e * 4);
    }

    // ---- final hT, cT ----
    {
        const int bglob = bgrp * 4 + quad;
        const int j = w * 16 + col;
        out[HT_OFF + ((size_t)n * B + bglob) * H + j] = hlast;
        out[CT_OFF + ((size_t)n * B + bglob) * H + j] = cst;
    }
}

extern "C" void kernel_launch(void* const* d_in, const int* in_sizes, int n_in,
                              void* d_out, int out_size, void* d_ws, size_t ws_size,
                              hipStream_t stream) {
    const float* X     = (const float*)d_in[0];
    const float* W_ih  = (const float*)d_in[1];
    const float* W_hh  = (const float*)d_in[2];
    const float* b_ih  = (const float*)d_in[3];
    const float* b_hh  = (const float*)d_in[4];
    const float* W_out = (const float*)d_in[5];
    const float* b_out = (const float*)d_in[6];
    float* out = (float*)d_out;

    const int xelems = 32 * 512 * 32;  // B*T*N
    const bool usebf = ws_size >= (size_t)xelems * sizeof(short);

    if (usebf) {
        short* Xb = (short*)d_ws;
        xcvt_kernel<<<dim3(xelems / 1024), dim3(256), 0, stream>>>(X, Xb, xelems);
        clstm_kernel<true><<<dim3(256), dim3(512), 0, stream>>>(
            X, Xb, W_ih, W_hh, b_ih, b_hh, W_out, b_out, out);
    } else {
        clstm_kernel<false><<<dim3(256), dim3(512), 0, stream>>>(
            X, nullptr, W_ih, W_hh, b_ih, b_hh, W_out, b_out, out);
    }
}